// Round 8
// baseline (261.784 us; speedup 1.0000x reference)
//
#include <hip/hip_runtime.h>
#include <cstdint>
#include <cstddef>

#define DI __device__ __forceinline__

using f32x4  = __attribute__((ext_vector_type(4))) float;
using bf16x8 = __attribute__((ext_vector_type(8))) short;
using u32x2  = __attribute__((ext_vector_type(2))) unsigned int;
using u32x4  = __attribute__((ext_vector_type(4))) unsigned int;

constexpr int NT = 16384;   // tokens
constexpr int NF = 4096;    // features

// fp32 -> bf16 round-to-nearest-even
DI unsigned short f2bf(float f) {
  union { float f; unsigned u; } v; v.f = f;
  unsigned u = v.u;
  u += 0x7fffu + ((u >> 16) & 1u);
  return (unsigned short)(u >> 16);
}

// async global->LDS, 16B per lane. lds dst is wave-uniform base; HW adds lane*16.
DI void gload_lds16(const void* g, void* l) {
  __builtin_amdgcn_global_load_lds(
      (const __attribute__((address_space(1))) unsigned int*)g,
      (__attribute__((address_space(3))) unsigned int*)l, 16, 0, 0);
}

// raw barrier with LDS-only drain (no vmcnt(0) — keeps prefetch loads in flight)
DI void bar_lgkm() {
  asm volatile("s_waitcnt lgkmcnt(0)" ::: "memory");
  __builtin_amdgcn_s_barrier();
  __builtin_amdgcn_sched_barrier(0);
}
// raw barrier with counted vmcnt (N newest VMEM ops may stay outstanding)
#define BAR_VM(N)                                              \
  do {                                                         \
    asm volatile("s_waitcnt vmcnt(" #N ")" ::: "memory");      \
    __builtin_amdgcn_s_barrier();                              \
    __builtin_amdgcn_sched_barrier(0);                         \
  } while (0)

// ---------------- prep: factor transpose + bf16 cast (verified r2) ----------------
// f0 [b][c][d] f32 -> f0s [d][b][c] bf16 ; f1 [a][b][c] f32 -> f1s bf16 (same layout)
__global__ void ks_prep(const float* __restrict__ f0, const float* __restrict__ f1,
                        unsigned short* __restrict__ f0s, unsigned short* __restrict__ f1s) {
  int tid = blockIdx.x * 256 + threadIdx.x;     // grid covers 2*262144
  if (tid < 262144) {
    int d = tid & 63, c = (tid >> 6) & 63, b = tid >> 12;
    f0s[d * 4096 + b * 64 + c] = f2bf(f0[tid]);
  } else {
    int t2 = tid - 262144;
    f1s[t2] = f2bf(f1[t2]);
  }
}

// ---------------- stage 1 v5: direct y'-chunk stores, no Ybuf ----------------
// block: 128 tokens x 8 d-planes (dg). wave (bt=wv&3, th=wv>>2) owns b-tile bt,
// token-half th, ALL 8 d's; f0 [8d][2kh] persistent in 64 VGPR. MFMA output
// lane(l15,lq) = y[t=l15][b=bt*16+lq*4+i][d=0..7] -> packed 16B y' chunk, stored
// directly to global. y' layout: byte = t*8192 + dg*1024 + b*16 + dloc*2.
__global__ __launch_bounds__(512, 4) void ks1(
    const float* __restrict__ x, const unsigned short* __restrict__ f0s,
    unsigned short* __restrict__ yp)
{
  __shared__ __align__(16) char L[65536];   // X dbuf: 2 x [8 d][32 t][64 c] bf16
  char* const Xb0 = L;
  char* const Xb1 = L + 32768;

  const int w  = blockIdx.x;
  const int tt = (w & 7) | ((w >> 6) << 3);   // siblings (dg 0..7) share XCD
  const int dg = (w >> 3) & 7;
  const long T0 = (long)tt * 128;

  const int tid = threadIdx.x, lane = tid & 63, wv = tid >> 6;
  const int l15 = lane & 15, lq = lane >> 4;
  const int bt = wv & 3, th = wv >> 2;

  // persistent A operand: f0s[dg*8+dd][bt*16+l15][c], 16 frags = 64 VGPR
  bf16x8 fA[8][2];
  #pragma unroll
  for (int dd = 0; dd < 8; ++dd)
    #pragma unroll
    for (int kh = 0; kh < 2; ++kh)
      fA[dd][kh] = *(const bf16x8*)(f0s + (size_t)(dg * 8 + dd) * 4096
                                    + (bt * 16 + l15) * 64 + kh * 32 + lq * 8);

  // x staging: thread -> (t 0..31, c-octet 0..7, d-quad 0..1); 8 f32x4 loads/iter
  const int st_t = tid >> 4, st_c0 = (tid >> 1) & 7, st_dq = tid & 1;
  const float* const xbase = x + (T0 + st_t) * (long)NF + st_c0 * 8 * 64 + dg * 8 + st_dq * 4;
  const int wkey = (st_t & 7) << 4;

  f32x4 v[8];
  auto issue = [&](int k) {
    const float* p = xbase + (long)k * 32 * NF;
    #pragma unroll
    for (int e = 0; e < 8; ++e) v[e] = *(const f32x4*)(p + e * 64);
  };
  // pack along d: per d, 8 c's -> one ds_write_b128 (4 per thread)
  auto stageX = [&](char* X) {
    #pragma unroll
    for (int j = 0; j < 4; ++j) {
      u32x4 wq;
      #pragma unroll
      for (int m = 0; m < 4; ++m)
        wq[m] = (unsigned)f2bf(v[2 * m][j]) | ((unsigned)f2bf(v[2 * m + 1][j]) << 16);
      *(u32x4*)(X + (st_dq * 4 + j) * 4096 + st_t * 128 + ((st_c0 * 16) ^ wkey)) = wq;
    }
  };

  issue(0);
  stageX(Xb0);
  issue(1);
  bar_lgkm();

  const int rkey = (l15 & 7) << 4;

  #pragma unroll
  for (int k = 0; k < 4; ++k) {
    const char* const Xs = ((k & 1) ? Xb1 : Xb0) + (th * 16 + l15) * 128;

    f32x4 acc[8];
    #pragma unroll
    for (int dd = 0; dd < 8; ++dd) {
      const char* Xd = Xs + dd * 4096;
      bf16x8 b0 = *(const bf16x8*)(Xd + ((lq * 16) ^ rkey));
      bf16x8 b1 = *(const bf16x8*)(Xd + ((64 + lq * 16) ^ rkey));
      acc[dd] = __builtin_amdgcn_mfma_f32_16x16x32_bf16(fA[dd][0], b0, (f32x4){0.f,0.f,0.f,0.f}, 0, 0, 0);
      acc[dd] = __builtin_amdgcn_mfma_f32_16x16x32_bf16(fA[dd][1], b1, acc[dd], 0, 0, 0);
    }

    if (k < 3) {
      stageX((k & 1) ? Xb0 : Xb1);   // consumes issue(k+1)
      if (k < 2) issue(k + 2);       // stays in flight across the barrier
    }

    // direct y' store: 4 x 16B chunks per lane (i=0..3), no LDS round-trip
    char* const yrow = (char*)yp + (T0 + k * 32 + th * 16 + l15) * 8192
                       + dg * 1024 + (bt * 16 + lq * 4) * 16;
    #pragma unroll
    for (int i = 0; i < 4; ++i) {
      u32x4 wq;
      #pragma unroll
      for (int m = 0; m < 4; ++m)
        wq[m] = (unsigned)f2bf(acc[2 * m][i]) | ((unsigned)f2bf(acc[2 * m + 1][i]) << 16);
      *(u32x4*)(yrow + i * 16) = wq;
    }

    bar_lgkm();
  }
}

// ---------------- stage 2 (r5 structure; counted-vmcnt raw barrier) ----------------
// block: 512 thr = 8 waves; wave wv owns a = ag*8+wv; block streams 256 tokens
// as 8 tiles of 32. global_load_lds stages full 128B y' runs; dbuf 2x32KB.
__global__ __launch_bounds__(512, 4) void ks2(
    const unsigned short* __restrict__ yp, const unsigned short* __restrict__ f1s,
    const float* __restrict__ bias, float* __restrict__ out)
{
  __shared__ __align__(16) char Yb[2][32768];   // [buf][32 t][8 dg][128 B]

  const int bid = blockIdx.x;
  const int ag  = bid & 7;
  const long T0 = (long)(bid >> 3) * 256;

  const int tid = threadIdx.x, lane = tid & 63, wv = tid >> 6;
  const int l15 = lane & 15, lq = lane >> 4;
  const int a = ag * 8 + wv;

  // persistent A operand: f1[a][b2][c2] (32 VGPR) + bias (16 VGPR)
  bf16x8 fa[4][2];
  #pragma unroll
  for (int bt = 0; bt < 4; ++bt)
    #pragma unroll
    for (int kh = 0; kh < 2; ++kh)
      fa[bt][kh] = *(const bf16x8*)(f1s + (size_t)a * 4096 + (bt * 16 + l15) * 64 + kh * 32 + lq * 8);
  f32x4 bv[4];
  #pragma unroll
  for (int bt = 0; bt < 4; ++bt)
    bv[bt] = *(const f32x4*)(bias + a * 64 + bt * 16 + lq * 4);

  // stage tile -> buf: wave wv loads rows {wv, 8+wv, 16+wv, 24+wv}; slot s=lane gets
  // global chunk g = s ^ (t&7) (involution; stays within the 128B dg-run -> coalesced)
  auto stage = [&](int tile, int buf) {
    #pragma unroll
    for (int i = 0; i < 4; ++i) {
      const int trow = i * 8 + wv;
      const int g = lane ^ (trow & 7);
      const char* src = (const char*)yp + (T0 + (long)tile * 32 + trow) * 8192
                        + ((g >> 3) << 10) + ag * 128 + (g & 7) * 16;
      gload_lds16(src, &Yb[buf][trow * 1024]);
    }
  };

  stage(0, 0);
  BAR_VM(0);   // prologue: tile 0 must be fully in LDS

  #pragma unroll
  for (int tile = 0; tile < 8; ++tile) {
    if (tile < 7) stage(tile + 1, (tile + 1) & 1);   // 4 loads, in flight during compute

    const char* Yt = Yb[tile & 1];
    const int sw = wv ^ (l15 & 7);           // swizzled chunk base (dg added per frag)
    #pragma unroll
    for (int tt = 0; tt < 2; ++tt) {
      const char* Yr = Yt + (tt * 16 + l15) * 1024;
      bf16x8 c0 = *(const bf16x8*)(Yr + ((lq * 8 + sw) * 16));            // dg = lq
      bf16x8 c1 = *(const bf16x8*)(Yr + (((4 + lq) * 8 + sw) * 16));      // dg = 4+lq
      f32x4 acc[4];
      #pragma unroll
      for (int bt = 0; bt < 4; ++bt) {
        acc[bt] = __builtin_amdgcn_mfma_f32_16x16x32_bf16(fa[bt][0], c0, (f32x4){0.f,0.f,0.f,0.f}, 0, 0, 0);
        acc[bt] = __builtin_amdgcn_mfma_f32_16x16x32_bf16(fa[bt][1], c1, acc[bt], 0, 0, 0);
      }
      float* op = out + (T0 + (long)tile * 32 + tt * 16 + l15) * NF + a * 64 + lq * 4;
      #pragma unroll
      for (int bt = 0; bt < 4; ++bt)
        *(f32x4*)(op + bt * 16) = acc[bt] + bv[bt];
    }

    // own loads(tile+1)[4] must land before barrier; stores(tile)[8] may drift
    BAR_VM(8);
  }
}

// ---------------- naive fp32 fallback (only if workspace too small) ----------------
__global__ void ks_naive(const float* __restrict__ x, const float* __restrict__ f0,
                         const float* __restrict__ f1, const float* __restrict__ bias,
                         float* __restrict__ out)
{
  __shared__ float xr[4096];
  __shared__ float yr[4096];
  long t = blockIdx.x;
  int tid = threadIdx.x;
  for (int i = tid; i < 4096; i += 256) xr[i] = x[t * 4096 + i];
  __syncthreads();
  for (int i = tid; i < 4096; i += 256) {
    int b = i >> 6, d = i & 63;
    float s = 0.f;
    for (int c = 0; c < 64; ++c) s += xr[c * 64 + d] * f0[(b * 64 + c) * 64 + d];
    yr[i] = s;
  }
  __syncthreads();
  for (int i = tid; i < 4096; i += 256) {
    int a = i >> 6;
    float s = bias[i];
    for (int c = 0; c < 64; ++c) s += yr[a * 64 + c] * f1[(size_t)i * 64 + c];
    out[t * 4096 + i] = s;
  }
}

extern "C" void kernel_launch(void* const* d_in, const int* in_sizes, int n_in,
                              void* d_out, int out_size, void* d_ws, size_t ws_size,
                              hipStream_t stream) {
  const float* x    = (const float*)d_in[0];
  const float* f0   = (const float*)d_in[1];
  const float* f1   = (const float*)d_in[2];
  const float* bias = (const float*)d_in[3];
  float* out = (float*)d_out;

  const size_t ybytes = (size_t)NT * NF * 2;          // 128 MB bf16 intermediate (y')
  const size_t fbytes = (size_t)64 * 64 * 64 * 2;     // 512 KB per factor
  if (ws_size >= ybytes + 2 * fbytes) {
    unsigned short* yw  = (unsigned short*)d_ws;
    unsigned short* f0s = yw + (size_t)NT * NF;
    unsigned short* f1s = f0s + 64 * 64 * 64;
    ks_prep<<<2048, 256, 0, stream>>>(f0, f1, f0s, f1s);
    ks1<<<1024, 512, 0, stream>>>(x, f0s, yw);
    ks2<<<512, 512, 0, stream>>>(yw, f1s, bias, out);
  } else {
    ks_naive<<<NT, 256, 0, stream>>>(x, f0, f1, bias, out);
  }
}

// Round 9
// 259.866 us; speedup vs baseline: 1.0074x; 1.0074x over previous
//
#include <hip/hip_runtime.h>
#include <cstdint>
#include <cstddef>

#define DI __device__ __forceinline__

using f32x4  = __attribute__((ext_vector_type(4))) float;
using bf16x8 = __attribute__((ext_vector_type(8))) short;
using u32x2  = __attribute__((ext_vector_type(2))) unsigned int;
using u32x4  = __attribute__((ext_vector_type(4))) unsigned int;

constexpr int NT = 16384;   // tokens
constexpr int NF = 4096;    // features

// y' layout: 16B chunk(cq, b, t) at byte ((cq*64 + b)*16384 + t)*16 ; chunk holds
// d = cq*8 .. cq*8+7 (bf16). Dense in t for ks1 stores AND ks2 loads.

// fp32 -> bf16 round-to-nearest-even
DI unsigned short f2bf(float f) {
  union { float f; unsigned u; } v; v.f = f;
  unsigned u = v.u;
  u += 0x7fffu + ((u >> 16) & 1u);
  return (unsigned short)(u >> 16);
}

// raw barrier with LDS-only drain (no vmcnt(0) — keeps prefetch loads in flight)
DI void bar_lgkm() {
  asm volatile("s_waitcnt lgkmcnt(0)" ::: "memory");
  __builtin_amdgcn_s_barrier();
  __builtin_amdgcn_sched_barrier(0);
}

// ---------------- prep: factor transpose + bf16 cast (verified r2) ----------------
// f0 [b][c][d] f32 -> f0s [d][b][c] bf16 ; f1 [a][b][c] f32 -> f1s bf16 (same layout)
__global__ void ks_prep(const float* __restrict__ f0, const float* __restrict__ f1,
                        unsigned short* __restrict__ f0s, unsigned short* __restrict__ f1s) {
  int tid = blockIdx.x * 256 + threadIdx.x;     // grid covers 2*262144
  if (tid < 262144) {
    int d = tid & 63, c = (tid >> 6) & 63, b = tid >> 12;
    f0s[d * 4096 + b * 64 + c] = f2bf(f0[tid]);
  } else {
    int t2 = tid - 262144;
    f1s[t2] = f2bf(f1[t2]);
  }
}

// ---------------- stage 1 v6: r8 structure + coalesced chunk-major y' stores --------
// block: 128 tokens x 8 d-planes (dg). wave (bt=wv&3, th=wv>>2): b-tile bt, token-half
// th, all 8 d's; f0 persistent in 64 VGPR. Store: 4 runs of 256B per instr.
__global__ __launch_bounds__(512, 4) void ks1(
    const float* __restrict__ x, const unsigned short* __restrict__ f0s,
    unsigned short* __restrict__ yp)
{
  __shared__ __align__(16) char L[65536];   // X dbuf: 2 x [8 d][32 t][64 c] bf16
  char* const Xb0 = L;
  char* const Xb1 = L + 32768;

  const int w  = blockIdx.x;
  const int tt = (w & 7) | ((w >> 6) << 3);   // siblings (dg 0..7) share XCD
  const int dg = (w >> 3) & 7;
  const long T0 = (long)tt * 128;

  const int tid = threadIdx.x, lane = tid & 63, wv = tid >> 6;
  const int l15 = lane & 15, lq = lane >> 4;
  const int bt = wv & 3, th = wv >> 2;

  // persistent A operand: f0s[dg*8+dd][bt*16+l15][c], 16 frags = 64 VGPR
  bf16x8 fA[8][2];
  #pragma unroll
  for (int dd = 0; dd < 8; ++dd)
    #pragma unroll
    for (int kh = 0; kh < 2; ++kh)
      fA[dd][kh] = *(const bf16x8*)(f0s + (size_t)(dg * 8 + dd) * 4096
                                    + (bt * 16 + l15) * 64 + kh * 32 + lq * 8);

  // x staging: thread -> (t 0..31, c-octet 0..7, d-quad 0..1); 8 f32x4 loads/iter
  const int st_t = tid >> 4, st_c0 = (tid >> 1) & 7, st_dq = tid & 1;
  const float* const xbase = x + (T0 + st_t) * (long)NF + st_c0 * 8 * 64 + dg * 8 + st_dq * 4;
  const int wkey = (st_t & 7) << 4;

  f32x4 v[8];
  auto issue = [&](int k) {
    const float* p = xbase + (long)k * 32 * NF;
    #pragma unroll
    for (int e = 0; e < 8; ++e) v[e] = *(const f32x4*)(p + e * 64);
  };
  // pack along d: per d, 8 c's -> one ds_write_b128 (4 per thread)
  auto stageX = [&](char* X) {
    #pragma unroll
    for (int j = 0; j < 4; ++j) {
      u32x4 wq;
      #pragma unroll
      for (int m = 0; m < 4; ++m)
        wq[m] = (unsigned)f2bf(v[2 * m][j]) | ((unsigned)f2bf(v[2 * m + 1][j]) << 16);
      *(u32x4*)(X + (st_dq * 4 + j) * 4096 + st_t * 128 + ((st_c0 * 16) ^ wkey)) = wq;
    }
  };

  issue(0);
  stageX(Xb0);
  issue(1);
  bar_lgkm();

  const int rkey = (l15 & 7) << 4;

  #pragma unroll
  for (int k = 0; k < 4; ++k) {
    const char* const Xs = ((k & 1) ? Xb1 : Xb0) + (th * 16 + l15) * 128;

    f32x4 acc[8];
    #pragma unroll
    for (int dd = 0; dd < 8; ++dd) {
      const char* Xd = Xs + dd * 4096;
      bf16x8 b0 = *(const bf16x8*)(Xd + ((lq * 16) ^ rkey));
      bf16x8 b1 = *(const bf16x8*)(Xd + ((64 + lq * 16) ^ rkey));
      acc[dd] = __builtin_amdgcn_mfma_f32_16x16x32_bf16(fA[dd][0], b0, (f32x4){0.f,0.f,0.f,0.f}, 0, 0, 0);
      acc[dd] = __builtin_amdgcn_mfma_f32_16x16x32_bf16(fA[dd][1], b1, acc[dd], 0, 0, 0);
    }

    if (k < 3) {
      stageX((k & 1) ? Xb0 : Xb1);   // consumes issue(k+1)
      if (k < 2) issue(k + 2);       // stays in flight across the barrier
    }

    // y' chunk store: chunk(cq=dg, b=bt*16+lq*4+i, t); lanes form 4 x 256B runs
    char* const ybase = (char*)yp
        + ((size_t)(dg * 64 + bt * 16 + lq * 4) * 16384
           + (T0 + k * 32 + th * 16 + l15)) * 16;
    #pragma unroll
    for (int i = 0; i < 4; ++i) {
      u32x4 wq;
      #pragma unroll
      for (int m = 0; m < 4; ++m)
        wq[m] = (unsigned)f2bf(acc[2 * m][i]) | ((unsigned)f2bf(acc[2 * m + 1][i]) << 16);
      *(u32x4*)(ybase + (size_t)i * 16384 * 16) = wq;
    }

    bar_lgkm();
  }
}

// ---------------- stage 2 v6: LDS-free, barrier-free, dense chunk loads ------------
// block: 512 thr = 8 waves; wave wv owns a = ag*8+wv; f1[a]+bias persistent in regs.
// B-frag = one y' chunk per lane: 4 x 256B dense runs per load instr. 256 tok/block.
__global__ __launch_bounds__(512, 4) void ks2(
    const unsigned short* __restrict__ yp, const unsigned short* __restrict__ f1s,
    const float* __restrict__ bias, float* __restrict__ out)
{
  const int bid = blockIdx.x;
  const int ag  = bid & 7;
  const long T0 = (long)(bid >> 3) * 256;

  const int tid = threadIdx.x, lane = tid & 63, wv = tid >> 6;
  const int l15 = lane & 15, lq = lane >> 4;
  const int a = ag * 8 + wv;

  // persistent A operand: f1[a][b2][c2] (32 VGPR) + bias (16 VGPR)
  bf16x8 fa[4][2];
  #pragma unroll
  for (int bt = 0; bt < 4; ++bt)
    #pragma unroll
    for (int kh = 0; kh < 2; ++kh)
      fa[bt][kh] = *(const bf16x8*)(f1s + (size_t)a * 4096 + (bt * 16 + l15) * 64 + kh * 32 + lq * 8);
  f32x4 bv[4];
  #pragma unroll
  for (int bt = 0; bt < 4; ++bt)
    bv[bt] = *(const f32x4*)(bias + a * 64 + bt * 16 + lq * 4);

  // B chunks: k-half 0 -> chunk(cq=lq, a, t); k-half 1 -> chunk(cq=4+lq, a, t)
  const char* const yb0 = (const char*)yp + ((size_t)(lq * 64 + a) * 16384 + T0 + l15) * 16;
  const char* const yb1 = yb0 + (size_t)4 * 64 * 16384 * 16;
  float* const ob = out + (T0 + l15) * (size_t)NF + a * 64 + lq * 4;

  auto compute = [&](int ti, bf16x8 c0, bf16x8 c1) {
    f32x4 acc[4];
    #pragma unroll
    for (int bt = 0; bt < 4; ++bt) {
      acc[bt] = __builtin_amdgcn_mfma_f32_16x16x32_bf16(fa[bt][0], c0, (f32x4){0.f,0.f,0.f,0.f}, 0, 0, 0);
      acc[bt] = __builtin_amdgcn_mfma_f32_16x16x32_bf16(fa[bt][1], c1, acc[bt], 0, 0, 0);
    }
    float* op = ob + (size_t)ti * 16 * NF;
    #pragma unroll
    for (int bt = 0; bt < 4; ++bt)
      *(f32x4*)(op + bt * 16) = acc[bt] + bv[bt];
  };

  // depth-2 named-register pipeline over 16 tiles of 16 tokens
  bf16x8 A0 = *(const bf16x8*)(yb0);
  bf16x8 A1 = *(const bf16x8*)(yb1);
  bf16x8 B0 = *(const bf16x8*)(yb0 + 256);
  bf16x8 B1 = *(const bf16x8*)(yb1 + 256);

  #pragma unroll
  for (int ti = 0; ti < 16; ti += 2) {
    bf16x8 nA0 = A0, nA1 = A1, nB0 = B0, nB1 = B1;
    if (ti + 2 < 16) {
      nA0 = *(const bf16x8*)(yb0 + (ti + 2) * 256);
      nA1 = *(const bf16x8*)(yb1 + (ti + 2) * 256);
    }
    compute(ti, A0, A1);
    if (ti + 3 < 16) {
      nB0 = *(const bf16x8*)(yb0 + (ti + 3) * 256);
      nB1 = *(const bf16x8*)(yb1 + (ti + 3) * 256);
    }
    compute(ti + 1, B0, B1);
    A0 = nA0; A1 = nA1; B0 = nB0; B1 = nB1;
  }
}

// ---------------- naive fp32 fallback (only if workspace too small) ----------------
__global__ void ks_naive(const float* __restrict__ x, const float* __restrict__ f0,
                         const float* __restrict__ f1, const float* __restrict__ bias,
                         float* __restrict__ out)
{
  __shared__ float xr[4096];
  __shared__ float yr[4096];
  long t = blockIdx.x;
  int tid = threadIdx.x;
  for (int i = tid; i < 4096; i += 256) xr[i] = x[t * 4096 + i];
  __syncthreads();
  for (int i = tid; i < 4096; i += 256) {
    int b = i >> 6, d = i & 63;
    float s = 0.f;
    for (int c = 0; c < 64; ++c) s += xr[c * 64 + d] * f0[(b * 64 + c) * 64 + d];
    yr[i] = s;
  }
  __syncthreads();
  for (int i = tid; i < 4096; i += 256) {
    int a = i >> 6;
    float s = bias[i];
    for (int c = 0; c < 64; ++c) s += yr[a * 64 + c] * f1[(size_t)i * 64 + c];
    out[t * 4096 + i] = s;
  }
}

extern "C" void kernel_launch(void* const* d_in, const int* in_sizes, int n_in,
                              void* d_out, int out_size, void* d_ws, size_t ws_size,
                              hipStream_t stream) {
  const float* x    = (const float*)d_in[0];
  const float* f0   = (const float*)d_in[1];
  const float* f1   = (const float*)d_in[2];
  const float* bias = (const float*)d_in[3];
  float* out = (float*)d_out;

  const size_t ybytes = (size_t)NT * NF * 2;          // 128 MB bf16 intermediate (y')
  const size_t fbytes = (size_t)64 * 64 * 64 * 2;     // 512 KB per factor
  if (ws_size >= ybytes + 2 * fbytes) {
    unsigned short* yw  = (unsigned short*)d_ws;
    unsigned short* f0s = yw + (size_t)NT * NF;
    unsigned short* f1s = f0s + 64 * 64 * 64;
    ks_prep<<<2048, 256, 0, stream>>>(f0, f1, f0s, f1s);
    ks1<<<1024, 512, 0, stream>>>(x, f0s, yw);
    ks2<<<512, 512, 0, stream>>>(yw, f1s, bias, out);
  } else {
    ks_naive<<<NT, 256, 0, stream>>>(x, f0, f1, bias, out);
  }
}

// Round 10
// 201.752 us; speedup vs baseline: 1.2976x; 1.2880x over previous
//
#include <hip/hip_runtime.h>
#include <cstdint>
#include <cstddef>

#define DI __device__ __forceinline__

using f32x4  = __attribute__((ext_vector_type(4))) float;
using bf16x8 = __attribute__((ext_vector_type(8))) short;
using u32x2  = __attribute__((ext_vector_type(2))) unsigned int;
using u32x4  = __attribute__((ext_vector_type(4))) unsigned int;

constexpr int NT = 16384;   // tokens
constexpr int NF = 4096;    // features

// fp32 -> bf16 round-to-nearest-even
DI unsigned short f2bf(float f) {
  union { float f; unsigned u; } v; v.f = f;
  unsigned u = v.u;
  u += 0x7fffu + ((u >> 16) & 1u);
  return (unsigned short)(u >> 16);
}

// async global->LDS, 16B per lane. lds dst is wave-uniform base; HW adds lane*16.
DI void gload_lds16(const void* g, void* l) {
  __builtin_amdgcn_global_load_lds(
      (const __attribute__((address_space(1))) unsigned int*)g,
      (__attribute__((address_space(3))) unsigned int*)l, 16, 0, 0);
}

// raw barrier with counted vmcnt (N newest VMEM ops may stay outstanding)
#define BAR_VM(N)                                              \
  do {                                                         \
    asm volatile("s_waitcnt vmcnt(" #N ")" ::: "memory");      \
    __builtin_amdgcn_s_barrier();                              \
    __builtin_amdgcn_sched_barrier(0);                         \
  } while (0)

// ---------------- prep: factor transpose + bf16 cast (verified r2) ----------------
// f0 [b][c][d] f32 -> f0s [d][b][c] bf16 ; f1 [a][b][c] f32 -> f1s bf16 (same layout)
__global__ void ks_prep(const float* __restrict__ f0, const float* __restrict__ f1,
                        unsigned short* __restrict__ f0s, unsigned short* __restrict__ f1s) {
  int tid = blockIdx.x * 256 + threadIdx.x;     // grid covers 2*262144
  if (tid < 262144) {
    int d = tid & 63, c = (tid >> 6) & 63, b = tid >> 12;
    f0s[d * 4096 + b * 64 + c] = f2bf(f0[tid]);
  } else {
    int t2 = tid - 262144;
    f1s[t2] = f2bf(f1[t2]);
  }
}

// ---------------- stage 1 (r6 verbatim — best measured ~107 µs) ----------------
// block: 128 tokens x 8 d-planes (wave wv owns d = dg*8+wv, f0 slice persistent in regs).
// y' layout: element = t*4096 + dg*512 + b*8 + dloc   (d-minor 16B chunks for stage2)
__global__ __launch_bounds__(512, 4) void ks1(
    const float* __restrict__ x, const unsigned short* __restrict__ f0s,
    unsigned short* __restrict__ yp)
{
  __shared__ __align__(16) char L[32768 + 2 * 16640];
  char* const Xb0 = L;
  char* const Xb1 = L + 16384;
  char* const Yb0 = L + 32768;
  char* const Yb1 = L + 32768 + 16640;

  const int w  = blockIdx.x;
  const int tt = (w & 7) | ((w >> 6) << 3);   // siblings (dg 0..7) share XCD
  const int dg = (w >> 3) & 7;
  const long T0 = (long)tt * 128;

  const int tid = threadIdx.x, lane = tid & 63, wv = tid >> 6;
  const int l15 = lane & 15, lq = lane >> 4;
  const int d = dg * 8 + wv;

  bf16x8 fA[4][2];
  #pragma unroll
  for (int bt = 0; bt < 4; ++bt)
    #pragma unroll
    for (int kh = 0; kh < 2; ++kh)
      fA[bt][kh] = *(const bf16x8*)(f0s + (size_t)d * 4096 + (bt * 16 + l15) * 64 + kh * 32 + lq * 8);

  const int st_t = tid >> 5, st_c0 = (tid >> 1) & 15, st_dq = tid & 1;
  const float* const xrow0 = x + (T0 + st_t) * (long)NF + dg * 8 + st_dq * 4;
  const int wkey = (st_t & 7) << 4;

  f32x4 r0, r1, r2, r3;
  auto issue = [&](int st) {
    const float* p = xrow0 + (long)st * 16 * NF + st_c0 * 4 * 64;
    r0 = *(const f32x4*)(p);
    r1 = *(const f32x4*)(p + 64);
    r2 = *(const f32x4*)(p + 128);
    r3 = *(const f32x4*)(p + 192);
  };
  auto stageX = [&](char* X) {
    #pragma unroll
    for (int e = 0; e < 4; ++e) {
      int p = st_dq * 4 + e;
      unsigned lo = (unsigned)f2bf(r0[e]) | ((unsigned)f2bf(r1[e]) << 16);
      unsigned hi = (unsigned)f2bf(r2[e]) | ((unsigned)f2bf(r3[e]) << 16);
      *(u32x2*)(X + p * 2048 + st_t * 128 + ((st_c0 * 8) ^ wkey)) = u32x2{lo, hi};
    }
  };

  issue(0);
  stageX(Xb0);
  issue(1);
  __syncthreads();

  const int rkey = (l15 & 7) << 4;

  for (int st = 0; st < 8; ++st) {
    char* const Xc = (st & 1) ? Xb1 : Xb0;
    char* const Xn = (st & 1) ? Xb0 : Xb1;
    char* const Yc = (st & 1) ? Yb1 : Yb0;

    const char* Xs = Xc + wv * 2048 + l15 * 128;
    bf16x8 bx0 = *(const bf16x8*)(Xs + ((0  + lq * 16) ^ rkey));
    bf16x8 bx1 = *(const bf16x8*)(Xs + ((64 + lq * 16) ^ rkey));
    f32x4 acc[4];
    #pragma unroll
    for (int bt = 0; bt < 4; ++bt) {
      acc[bt] = __builtin_amdgcn_mfma_f32_16x16x32_bf16(fA[bt][0], bx0, (f32x4){0.f,0.f,0.f,0.f}, 0, 0, 0);
      acc[bt] = __builtin_amdgcn_mfma_f32_16x16x32_bf16(fA[bt][1], bx1, acc[bt], 0, 0, 0);
    }

    {
      char* Yw = Yc + l15 * 1040 + wv * 2;
      #pragma unroll
      for (int bt = 0; bt < 4; ++bt)
        #pragma unroll
        for (int i = 0; i < 4; ++i)
          *(unsigned short*)(Yw + (bt * 16 + lq * 4 + i) * 16) = f2bf(acc[bt][i]);
    }

    stageX(Xn);
    issue(st + 2 <= 7 ? st + 2 : 7);
    __syncthreads();

    {
      const char* Yr = Yc;
      #pragma unroll
      for (int h = 0; h < 2; ++h) {
        int t = (tid >> 6) + h * 8;
        int c16 = tid & 63;
        u32x4 v = *(const u32x4*)(Yr + t * 1040 + c16 * 16);
        *(u32x4*)(yp + (T0 + st * 16 + t) * (size_t)NF + dg * 512 + c16 * 8) = v;
      }
    }
  }
}

// ---------------- stage 2 v7: 4-buffer, depth-3 prefetch, derived vmcnt ----------
// block: 512 thr = 8 waves; wave wv owns a = ag*8+wv; 128 tokens as 8 tiles of 16.
// Tile staged ~2.5 compute phases before use; exact per-iter vmcnt keeps prefetch
// loads in flight across raw barriers (T3+T4 with derived waits).
__global__ __launch_bounds__(512, 4) void ks2(
    const unsigned short* __restrict__ yp, const unsigned short* __restrict__ f1s,
    const float* __restrict__ bias, float* __restrict__ out)
{
  __shared__ __align__(16) char Yb[4][16384];   // 4 bufs x [16 t][8 dg][128 B]

  const int bid = blockIdx.x;
  const int ag  = bid & 7;
  const long T0 = (long)(bid >> 3) * 128;

  const int tid = threadIdx.x, lane = tid & 63, wv = tid >> 6;
  const int l15 = lane & 15, lq = lane >> 4;
  const int a = ag * 8 + wv;

  // persistent A operand: f1[a][b2][c2] (32 VGPR) + bias (16 VGPR)
  bf16x8 fa[4][2];
  #pragma unroll
  for (int bt = 0; bt < 4; ++bt)
    #pragma unroll
    for (int kh = 0; kh < 2; ++kh)
      fa[bt][kh] = *(const bf16x8*)(f1s + (size_t)a * 4096 + (bt * 16 + l15) * 64 + kh * 32 + lq * 8);
  f32x4 bv[4];
  #pragma unroll
  for (int bt = 0; bt < 4; ++bt)
    bv[bt] = *(const f32x4*)(bias + a * 64 + bt * 16 + lq * 4);

  // stage one 16-token tile -> buf tile&3: wave wv loads rows {wv, 8+wv};
  // slot s holds global chunk g = s ^ (trow&7) (involution, stays in 128B dg-run)
  auto stage = [&](int tile) {
    char* const dst = Yb[tile & 3];
    #pragma unroll
    for (int i = 0; i < 2; ++i) {
      const int trow = i * 8 + wv;
      const int g = lane ^ (trow & 7);
      const char* src = (const char*)yp + (T0 + (long)tile * 16 + trow) * 8192
                        + ((g >> 3) << 10) + ag * 128 + (g & 7) * 16;
      gload_lds16(src, dst + trow * 1024);
    }
  };

  stage(0); stage(1); stage(2);
  BAR_VM(4);                 // 6 outstanding; all-but-4 -> stage(0) resident

  #pragma unroll
  for (int j = 0; j < 8; ++j) {
    if (j + 3 < 8) stage(j + 3);      // 2 loads, consumed ~2.5 iters later

    const char* Yr = Yb[j & 3] + l15 * 1024;
    const int sw = wv ^ (l15 & 7);
    bf16x8 c0 = *(const bf16x8*)(Yr + ((lq * 8 + sw) * 16));          // dg = lq
    bf16x8 c1 = *(const bf16x8*)(Yr + (((4 + lq) * 8 + sw) * 16));    // dg = 4+lq
    f32x4 acc[4];
    #pragma unroll
    for (int bt = 0; bt < 4; ++bt) {
      acc[bt] = __builtin_amdgcn_mfma_f32_16x16x32_bf16(fa[bt][0], c0, (f32x4){0.f,0.f,0.f,0.f}, 0, 0, 0);
      acc[bt] = __builtin_amdgcn_mfma_f32_16x16x32_bf16(fa[bt][1], c1, acc[bt], 0, 0, 0);
    }
    float* op = out + (T0 + (long)j * 16 + l15) * NF + a * 64 + lq * 4;
    #pragma unroll
    for (int bt = 0; bt < 4; ++bt)
      *(f32x4*)(op + bt * 16) = acc[bt] + bv[bt];

    // exact own-wave counts so stage(j+1) is resident before the barrier:
    // ops newer than stage(j+1) = later stages (2 each) + stores (4/iter)
    switch (j) {
      case 0: BAR_VM(8);  break;
      case 1: BAR_VM(12); break;
      case 2: BAR_VM(16); break;
      case 3: BAR_VM(16); break;
      case 4: BAR_VM(16); break;
      case 5: BAR_VM(14); break;
      case 6: BAR_VM(12); break;
      default: break;            // j==7: last tile
    }
  }
}

// ---------------- naive fp32 fallback (only if workspace too small) ----------------
__global__ void ks_naive(const float* __restrict__ x, const float* __restrict__ f0,
                         const float* __restrict__ f1, const float* __restrict__ bias,
                         float* __restrict__ out)
{
  __shared__ float xr[4096];
  __shared__ float yr[4096];
  long t = blockIdx.x;
  int tid = threadIdx.x;
  for (int i = tid; i < 4096; i += 256) xr[i] = x[t * 4096 + i];
  __syncthreads();
  for (int i = tid; i < 4096; i += 256) {
    int b = i >> 6, d = i & 63;
    float s = 0.f;
    for (int c = 0; c < 64; ++c) s += xr[c * 64 + d] * f0[(b * 64 + c) * 64 + d];
    yr[i] = s;
  }
  __syncthreads();
  for (int i = tid; i < 4096; i += 256) {
    int a = i >> 6;
    float s = bias[i];
    for (int c = 0; c < 64; ++c) s += yr[a * 64 + c] * f1[(size_t)i * 64 + c];
    out[t * 4096 + i] = s;
  }
}

extern "C" void kernel_launch(void* const* d_in, const int* in_sizes, int n_in,
                              void* d_out, int out_size, void* d_ws, size_t ws_size,
                              hipStream_t stream) {
  const float* x    = (const float*)d_in[0];
  const float* f0   = (const float*)d_in[1];
  const float* f1   = (const float*)d_in[2];
  const float* bias = (const float*)d_in[3];
  float* out = (float*)d_out;

  const size_t ybytes = (size_t)NT * NF * 2;          // 128 MB bf16 intermediate (y')
  const size_t fbytes = (size_t)64 * 64 * 64 * 2;     // 512 KB per factor
  if (ws_size >= ybytes + 2 * fbytes) {
    unsigned short* yw  = (unsigned short*)d_ws;
    unsigned short* f0s = yw + (size_t)NT * NF;
    unsigned short* f1s = f0s + 64 * 64 * 64;
    ks_prep<<<2048, 256, 0, stream>>>(f0, f1, f0s, f1s);
    ks1<<<1024, 512, 0, stream>>>(x, f0s, yw);
    ks2<<<1024, 512, 0, stream>>>(yw, f1s, bias, out);
  } else {
    ks_naive<<<NT, 256, 0, stream>>>(x, f0, f1, bias, out);
  }
}